// Round 1
// baseline (481.423 us; speedup 1.0000x reference)
//
#include <hip/hip_runtime.h>
#include <math.h>

#define N_NODES 100000
#define DEG_E   32
#define T_CH    16
#define N_LAYERS 2
#define E_EDGES (N_NODES * DEG_E)

// ---------------- transpose x [T,N] -> xt [N,T] ----------------
// idx = t*N + n (consecutive n -> coalesced read of x); write xt[n*16+t] (cached)
__global__ void k_transpose_in(const float* __restrict__ x, float* __restrict__ xt) {
    int idx = blockIdx.x * blockDim.x + threadIdx.x;
    if (idx >= N_NODES * T_CH) return;
    int t = idx / N_NODES;
    int n = idx - t * N_NODES;
    xt[n * T_CH + t] = x[idx];
}

// ---------------- degree histogram over src (run-length compressed) ----------
// each thread scans 32 consecutive edges; src is sorted so this is ~1 atomic/thread
__global__ void k_degree(const int* __restrict__ src, int* __restrict__ deg, int E) {
    int chunk = blockIdx.x * blockDim.x + threadIdx.x;
    int e0 = chunk * DEG_E;
    if (e0 >= E) return;
    int e1 = min(e0 + DEG_E, E);
    int cur = src[e0];
    int cnt = 1;
    for (int e = e0 + 1; e < e1; ++e) {
        int s = src[e];
        if (s == cur) {
            cnt++;
        } else {
            atomicAdd(&deg[cur], cnt);
            cur = s;
            cnt = 1;
        }
    }
    atomicAdd(&deg[cur], cnt);
}

// ---------------- scatter: aggr[dst][t] += xt[src][t] ------------------------
// 16 lanes per edge; per-edge weight is factored out (depends only on dst)
__global__ void k_scatter(const int* __restrict__ src, const int* __restrict__ dst,
                          const float* __restrict__ xt, float* __restrict__ aggr) {
    long long tid = (long long)blockIdx.x * blockDim.x + threadIdx.x;
    if (tid >= (long long)E_EDGES * T_CH) return;
    int e = (int)(tid >> 4);
    int t = (int)(tid & 15);
    int s = src[e];
    int d = dst[e];
    atomicAdd(&aggr[d * T_CH + t], xt[s * T_CH + t]);
}

// ---------------- combine (intermediate layers): writes [N,T] ----------------
__global__ void k_combine_nt(const float* __restrict__ xt, const float* __restrict__ aggr,
                             const int* __restrict__ deg,
                             const float* __restrict__ alpha1, const float* __restrict__ gamma,
                             const float* __restrict__ bias, int layer,
                             float* __restrict__ out_nt) {
    int idx = blockIdx.x * blockDim.x + threadIdx.x;
    if (idx >= N_NODES * T_CH) return;
    float a1 = alpha1[layer];
    float g  = gamma[layer];
    float b  = bias[layer];
    float dp = 1.0f / (1.0f + expf(-g));   // sigmoid(gamma)
    float sw = expf(a1);                    // self weight
    float nw = sw * tanhf(a1);              // neighbor weight
    int n = idx >> 4;
    float ld = logf((float)deg[n]);
    float w1 = expf(dp * ld);               // deg^dp
    float w2 = expf((dp - 1.0f) * ld);      // deg^(dp-1)
    out_nt[idx] = sw * w1 * xt[idx] + nw * w2 * aggr[idx] + b;
}

// ---------------- combine (final layer): writes [T,N] to d_out ---------------
__global__ void k_combine_final(const float* __restrict__ xt, const float* __restrict__ aggr,
                                const int* __restrict__ deg,
                                const float* __restrict__ alpha1, const float* __restrict__ gamma,
                                const float* __restrict__ bias, int layer,
                                float* __restrict__ out_tn) {
    int idx = blockIdx.x * blockDim.x + threadIdx.x;   // idx = t*N + n  (coalesced store)
    if (idx >= N_NODES * T_CH) return;
    float a1 = alpha1[layer];
    float g  = gamma[layer];
    float b  = bias[layer];
    float dp = 1.0f / (1.0f + expf(-g));
    float sw = expf(a1);
    float nw = sw * tanhf(a1);
    int t = idx / N_NODES;
    int n = idx - t * N_NODES;
    int j = n * T_CH + t;
    float ld = logf((float)deg[n]);
    float w1 = expf(dp * ld);
    float w2 = expf((dp - 1.0f) * ld);
    out_tn[idx] = sw * w1 * xt[j] + nw * w2 * aggr[j] + b;
}

extern "C" void kernel_launch(void* const* d_in, const int* in_sizes, int n_in,
                              void* d_out, int out_size, void* d_ws, size_t ws_size,
                              hipStream_t stream) {
    const float* x      = (const float*)d_in[0];
    const int*   ei     = (const int*)d_in[1];
    const float* alpha1 = (const float*)d_in[2];
    const float* gamma  = (const float*)d_in[3];
    const float* bias   = (const float*)d_in[4];
    float* out = (float*)d_out;

    const int* src = ei;
    const int* dst = ei + E_EDGES;

    const int NT = N_NODES * T_CH;
    float* xtA  = (float*)d_ws;          // [N,T] 6.4 MB
    float* xtB  = xtA + NT;              // [N,T] 6.4 MB
    float* aggr = xtB + NT;              // [N,T] 6.4 MB
    int*   deg  = (int*)(aggr + NT);     // [N]   0.4 MB

    const int B = 256;
    const int grid_nt      = (NT + B - 1) / B;
    const int grid_deg     = (E_EDGES / DEG_E + B - 1) / B;
    const long long scat_threads = (long long)E_EDGES * T_CH;
    const int grid_scatter = (int)((scat_threads + B - 1) / B);

    // init: deg = 0, transpose x
    hipMemsetAsync(deg, 0, N_NODES * sizeof(int), stream);
    k_transpose_in<<<grid_nt, B, 0, stream>>>(x, xtA);
    k_degree<<<grid_deg, B, 0, stream>>>(src, deg, E_EDGES);

    // layer 0
    hipMemsetAsync(aggr, 0, NT * sizeof(float), stream);
    k_scatter<<<grid_scatter, B, 0, stream>>>(src, dst, xtA, aggr);
    k_combine_nt<<<grid_nt, B, 0, stream>>>(xtA, aggr, deg, alpha1, gamma, bias, 0, xtB);

    // layer 1 (final)
    hipMemsetAsync(aggr, 0, NT * sizeof(float), stream);
    k_scatter<<<grid_scatter, B, 0, stream>>>(src, dst, xtB, aggr);
    k_combine_final<<<grid_nt, B, 0, stream>>>(xtB, aggr, deg, alpha1, gamma, bias, 1, out);
}